// Round 7
// baseline (1094.972 us; speedup 1.0000x reference)
//
#include <hip/hip_runtime.h>
#include <math.h>

#define TPB 256
#define PMAX 32        // max partitions
#define PSH 12         // partition = dst >> 12 (4096 nodes/partition; n <= 131072)
#define PW  4096       // nodes per partition
#define CAP 320        // LDS staging entries per partition (flush >=64; worst 63+256=319)

__device__ __forceinline__ float leaky02(float x) { return x > 0.f ? x : 0.2f * x; }
__device__ __forceinline__ float eluf(float x) { return x > 0.f ? x : (expf(x) - 1.f); }

// ====================== CSR build: packed partition-staged counting sort ======================

__global__ void zero_kernel(int* __restrict__ p, int n) {
  int i = blockIdx.x * blockDim.x + threadIdx.x;
  if (i < n) p[i] = 0;
}

// per-partition edge counts (LDS-aggregated)
__global__ void phist_kernel(const int* __restrict__ dst, int E, int n, int* __restrict__ pcount) {
  __shared__ int lh[PMAX];
  if (threadIdx.x < PMAX) lh[threadIdx.x] = 0;
  __syncthreads();
  int stride = gridDim.x * blockDim.x;
  for (int idx = blockIdx.x * blockDim.x + threadIdx.x; idx < E + n; idx += stride) {
    int dd = (idx < E) ? dst[idx] : (idx - E);
    atomicAdd(&lh[dd >> PSH], 1);
  }
  __syncthreads();
  if (threadIdx.x < PMAX) {
    int v = lh[threadIdx.x];
    if (v) atomicAdd(&pcount[threadIdx.x], v);
  }
}

// exclusive scan of NP partition counts -> pbase (immutable, NP+1 entries) + pcursor (mutable)
__global__ void pscan_kernel(const int* __restrict__ pcount, int* __restrict__ pbase,
                             int* __restrict__ pcursor, int NP) {
  if (threadIdx.x == 0) {
    int acc = 0;
    for (int q = 0; q < NP; q++) {
      pbase[q] = acc; pcursor[q] = acc; acc += pcount[q];
    }
    pbase[NP] = acc;
  }
}

// LDS-buffered partition scatter of PACKED (src<<12 | dst&0xFFF) words.
__global__ __launch_bounds__(256) void stage_kernel(const int* __restrict__ src,
                                                    const int* __restrict__ dst,
                                                    int E, int n, int NP,
                                                    int* __restrict__ pcursor,
                                                    unsigned* __restrict__ pstage) {
  __shared__ unsigned buf[PMAX][CAP];
  __shared__ int cnt[PMAX];
  __shared__ int gbase;
  if (threadIdx.x < PMAX) cnt[threadIdx.x] = 0;
  __syncthreads();
  int Etot = E + n;
  int tiles = (Etot + TPB - 1) / TPB;
  for (int t = blockIdx.x; t < tiles; t += gridDim.x) {
    int idx = t * TPB + threadIdx.x;
    if (idx < Etot) {
      int ss, dd;
      if (idx < E) { ss = src[idx]; dd = dst[idx]; }
      else         { ss = dd = idx - E; }
      int p = dd >> PSH;
      int pos = atomicAdd(&cnt[p], 1);   // < CAP guaranteed by flush policy
      buf[p][pos] = ((unsigned)ss << PSH) | (unsigned)(dd & (PW - 1));
    }
    __syncthreads();
    for (int q = 0; q < NP; q++) {
      int c = cnt[q];
      if (c >= 64) {
        if (threadIdx.x == 0) gbase = atomicAdd(&pcursor[q], c);
        __syncthreads();
        for (int j = threadIdx.x; j < c; j += TPB) pstage[gbase + j] = buf[q][j];
        __syncthreads();
        if (threadIdx.x == 0) cnt[q] = 0;
        __syncthreads();
      }
    }
  }
  for (int q = 0; q < NP; q++) {
    int c = cnt[q];
    if (c > 0) {
      if (threadIdx.x == 0) gbase = atomicAdd(&pcursor[q], c);
      __syncthreads();
      for (int j = threadIdx.x; j < c; j += TPB) pstage[gbase + j] = buf[q][j];
      __syncthreads();
      if (threadIdx.x == 0) cnt[q] = 0;
      __syncthreads();
    }
  }
}

// LDS-aggregated degree histogram: 8 blocks per partition, 4096-counter LDS window.
__global__ __launch_bounds__(256) void deg_hist_kernel(const unsigned* __restrict__ pstage,
                                                       const int* __restrict__ pbase,
                                                       int NP, int n, int* __restrict__ deg) {
  __shared__ int lh[PW];
  int p = blockIdx.x >> 3;
  if (p >= NP) return;
  int slice = blockIdx.x & 7;
  for (int j = threadIdx.x; j < PW; j += TPB) lh[j] = 0;
  __syncthreads();
  int base = pbase[p];
  int cnt_p = pbase[p + 1] - base;
  for (int i = slice * TPB + threadIdx.x; i < cnt_p; i += 8 * TPB)
    atomicAdd(&lh[pstage[base + i] & (PW - 1)], 1);
  __syncthreads();
  int nodebase = p << PSH;
  for (int j = threadIdx.x; j < PW; j += TPB) {
    int v = lh[j];
    if (v) atomicAdd(&deg[nodebase + j], v);
  }
}

// per-block reduce of deg -> bsum[block]
__global__ void scanA_kernel(const int* __restrict__ deg, int n, int* __restrict__ bsum) {
  __shared__ int sm[TPB];
  int i = blockIdx.x * TPB + threadIdx.x;
  sm[threadIdx.x] = (i < n) ? deg[i] : 0;
  __syncthreads();
  for (int off = TPB / 2; off >= 1; off >>= 1) {
    if (threadIdx.x < off) sm[threadIdx.x] += sm[threadIdx.x + off];
    __syncthreads();
  }
  if (threadIdx.x == 0) bsum[blockIdx.x] = sm[0];
}

// single block of 512: exclusive scan of bsum in place (nb <= 512)
__global__ void scanB_kernel(int* __restrict__ bsum, int nb) {
  __shared__ int sm[512];
  int t = threadIdx.x;
  int v = (t < nb) ? bsum[t] : 0;
  sm[t] = v;
  __syncthreads();
  for (int off = 1; off < 512; off <<= 1) {
    int a = (t >= off) ? sm[t - off] : 0;
    __syncthreads();
    sm[t] += a;
    __syncthreads();
  }
  if (t < nb) bsum[t] = sm[t] - v;  // exclusive
}

// per-block exclusive scan + block offset -> rowptr, cursor
__global__ void scanC_kernel(const int* __restrict__ deg, const int* __restrict__ boff, int n,
                             int* __restrict__ rowptr, int* __restrict__ cursor) {
  __shared__ int sm[TPB];
  int t = threadIdx.x;
  int i = blockIdx.x * TPB + t;
  int v = (i < n) ? deg[i] : 0;
  sm[t] = v;
  __syncthreads();
  for (int off = 1; off < TPB; off <<= 1) {
    int a = (t >= off) ? sm[t - off] : 0;
    __syncthreads();
    sm[t] += a;
    __syncthreads();
  }
  if (i < n) {
    int ex = boff[blockIdx.x] + sm[t] - v;
    rowptr[i] = ex;
    cursor[i] = ex;
  }
}

// final scatter from packed stage; XCD-swizzled chunks keep write windows L2-resident.
__global__ void final_scatter_kernel(const unsigned* __restrict__ pstage, int Etot, int G8,
                                     const int* __restrict__ pbase, int NP,
                                     int* __restrict__ cursor, int* __restrict__ csr_src) {
  __shared__ int spb[PMAX + 1];
  for (int j = threadIdx.x; j <= NP; j += TPB) spb[j] = pbase[j];
  __syncthreads();
  int b = blockIdx.x;
  int c = (b & 7) * G8 + (b >> 3);
  int idx = c * TPB + threadIdx.x;
  if (idx >= Etot) return;
  unsigned v = pstage[idx];
  // binary search: largest p with spb[p] <= idx
  int lo = 0, hi = NP - 1;
  while (lo < hi) {
    int mid = (lo + hi + 1) >> 1;
    if (spb[mid] <= idx) lo = mid; else hi = mid - 1;
  }
  int dst = (lo << PSH) | (int)(v & (PW - 1));
  int src = (int)(v >> PSH);
  int pos = atomicAdd(&cursor[dst], 1);
  csr_src[pos] = src;
}

// ====================== node transform (h = x@W, attn logits) ======================

template<int IN, int OUT, int H>
__global__ void transform_kernel(const float* __restrict__ x, const float* __restrict__ W,
                                 const float* __restrict__ a_src, const float* __restrict__ a_dst,
                                 float* __restrict__ h, float* __restrict__ asrc,
                                 float* __restrict__ adst, int n) {
  __shared__ float sW[IN * OUT];
  __shared__ float sa[2 * OUT];
  for (int i = threadIdx.x; i < IN * OUT; i += blockDim.x) sW[i] = W[i];
  if (threadIdx.x < OUT) {
    sa[threadIdx.x] = a_src[threadIdx.x];
    sa[OUT + threadIdx.x] = a_dst[threadIdx.x];
  }
  __syncthreads();
  int i = blockIdx.x * blockDim.x + threadIdx.x;
  if (i >= n) return;
  float xv[IN];
#pragma unroll
  for (int k = 0; k < IN; k++) xv[k] = x[(size_t)i * IN + k];
  float hv[OUT];
#pragma unroll
  for (int j = 0; j < OUT; j++) {
    float acc = 0.f;
#pragma unroll
    for (int k = 0; k < IN; k++) acc += xv[k] * sW[k * OUT + j];
    hv[j] = acc;
    h[(size_t)i * OUT + j] = acc;
  }
#pragma unroll
  for (int hh = 0; hh < H; hh++) {
    float as = 0.f, ad = 0.f;
#pragma unroll
    for (int c = 0; c < 16; c++) {
      as += hv[hh * 16 + c] * sa[hh * 16 + c];
      ad += hv[hh * 16 + c] * sa[OUT + hh * 16 + c];
    }
    asrc[i * H + hh] = as;
    adst[i * H + hh] = ad;
  }
}

// ====================== per-node GAT aggregation (1 wave / dst node) ======================

__global__ __launch_bounds__(256) void node_gat12(
    const int* __restrict__ rowptr, const int* __restrict__ deg,
    const int* __restrict__ csr_src,
    const float* __restrict__ asrc,  // [n*2]
    const float* __restrict__ adst,  // [n*2]
    const float* __restrict__ hfeat, // [n*32]
    const float* __restrict__ bias,  // [32]
    float* __restrict__ outb,        // [n*32]
    int n) {
  __shared__ int   s_sidx[4][64];
  __shared__ float s_a0[4][64];
  __shared__ float s_a1[4][64];
  int wid = threadIdx.x >> 6;
  int lane = threadIdx.x & 63;
  int i = (blockIdx.x * blockDim.x + threadIdx.x) >> 6;
  if (i >= n) return;
  int start = rowptr[i];
  int d = deg[i];
  float ad0 = adst[i * 2 + 0];
  float ad1 = adst[i * 2 + 1];

  // ---- pass 1: online softmax (max + expsum in one sweep) ----
  float m0 = -3.4e38f, s0 = 0.f, m1 = -3.4e38f, s1 = 0.f;
  for (int k = lane; k < d; k += 64) {
    int sidx = csr_src[start + k];
    float2 av = ((const float2*)asrc)[sidx];
    float e0 = leaky02(av.x + ad0);
    float e1 = leaky02(av.y + ad1);
    float nm0 = fmaxf(m0, e0);
    s0 = s0 * expf(m0 - nm0) + expf(e0 - nm0);
    m0 = nm0;
    float nm1 = fmaxf(m1, e1);
    s1 = s1 * expf(m1 - nm1) + expf(e1 - nm1);
    m1 = nm1;
  }
#pragma unroll
  for (int off = 32; off >= 1; off >>= 1) {
    float mo0 = __shfl_xor(m0, off), so0 = __shfl_xor(s0, off);
    float nm0 = fmaxf(m0, mo0);
    s0 = s0 * expf(m0 - nm0) + so0 * expf(mo0 - nm0);
    m0 = nm0;
    float mo1 = __shfl_xor(m1, off), so1 = __shfl_xor(s1, off);
    float nm1 = fmaxf(m1, mo1);
    s1 = s1 * expf(m1 - nm1) + so1 * expf(mo1 - nm1);
    m1 = nm1;
  }
  float inv0 = 1.f / (s0 + 1e-16f);
  float inv1 = 1.f / (s1 + 1e-16f);

  // ---- pass 2: per-edge alpha staged in LDS; strided gather-accumulate ----
  int head = (lane >> 4) & 1;
  int c = lane & 31;
  int half = lane >> 5;
  float acc = 0.f;
  for (int base = 0; base < d; base += 64) {
    int k = base + lane;
    int sidx = 0;
    float a0 = 0.f, a1 = 0.f;
    if (k < d) {
      sidx = csr_src[start + k];
      float2 av = ((const float2*)asrc)[sidx];
      a0 = expf(leaky02(av.x + ad0) - m0) * inv0;
      a1 = expf(leaky02(av.y + ad1) - m1) * inv1;
    }
    s_sidx[wid][lane] = sidx;
    s_a0[wid][lane] = a0;
    s_a1[wid][lane] = a1;
    int cnt = min(64, d - base);
    for (int jj = half; jj < cnt; jj += 2) {
      int sb = s_sidx[wid][jj];
      float wb = head ? s_a1[wid][jj] : s_a0[wid][jj];
      acc += wb * hfeat[(size_t)sb * 32 + c];
    }
  }
  acc += __shfl_xor(acc, 32);
  if (lane < 32) {
    outb[(size_t)i * 32 + c] = eluf(acc + bias[c]);
  }
}

__global__ __launch_bounds__(256) void node_gat3(
    const int* __restrict__ rowptr, const int* __restrict__ deg,
    const int* __restrict__ csr_src,
    const float* __restrict__ asrc,  // [n]
    const float* __restrict__ adst,  // [n]
    const float* __restrict__ hfeat, // [n*16]
    const float* __restrict__ b3,    // [16]
    const float* __restrict__ Wout,  // [16]
    const float* __restrict__ bout,  // [1]
    float* __restrict__ out,         // [n] sigmoid ++ [n*16] embeddings
    int n) {
  __shared__ int   s_sidx[4][64];
  __shared__ float s_a0[4][64];
  int wid = threadIdx.x >> 6;
  int lane = threadIdx.x & 63;
  int i = (blockIdx.x * blockDim.x + threadIdx.x) >> 6;
  if (i >= n) return;
  int start = rowptr[i];
  int d = deg[i];
  float ad0 = adst[i];

  float m0 = -3.4e38f, s0 = 0.f;
  for (int k = lane; k < d; k += 64) {
    int sidx = csr_src[start + k];
    float e0 = leaky02(asrc[sidx] + ad0);
    float nm0 = fmaxf(m0, e0);
    s0 = s0 * expf(m0 - nm0) + expf(e0 - nm0);
    m0 = nm0;
  }
#pragma unroll
  for (int off = 32; off >= 1; off >>= 1) {
    float mo = __shfl_xor(m0, off), so = __shfl_xor(s0, off);
    float nm = fmaxf(m0, mo);
    s0 = s0 * expf(m0 - nm) + so * expf(mo - nm);
    m0 = nm;
  }
  float inv = 1.f / (s0 + 1e-16f);

  int c = lane & 15;
  int quarter = lane >> 4;
  float acc = 0.f;
  for (int base = 0; base < d; base += 64) {
    int k = base + lane;
    int sidx = 0;
    float a0 = 0.f;
    if (k < d) {
      sidx = csr_src[start + k];
      a0 = expf(leaky02(asrc[sidx] + ad0) - m0) * inv;
    }
    s_sidx[wid][lane] = sidx;
    s_a0[wid][lane] = a0;
    int cnt = min(64, d - base);
    for (int jj = quarter; jj < cnt; jj += 4) {
      int sb = s_sidx[wid][jj];
      acc += s_a0[wid][jj] * hfeat[(size_t)sb * 16 + c];
    }
  }
  acc += __shfl_xor(acc, 32);
  acc += __shfl_xor(acc, 16);

  float v = 0.f, z = 0.f;
  if (lane < 16) {
    v = eluf(acc + b3[c]);
    out[(size_t)n + (size_t)i * 16 + c] = v;
    z = v * Wout[c];
  }
#pragma unroll
  for (int off = 8; off >= 1; off >>= 1) z += __shfl_xor(z, off);
  if (lane == 0) out[i] = 1.f / (1.f + expf(-(z + bout[0])));
}

// ====================== launch ======================

extern "C" void kernel_launch(void* const* d_in, const int* in_sizes, int n_in,
                              void* d_out, int out_size, void* d_ws, size_t ws_size,
                              hipStream_t stream) {
  const float* x    = (const float*)d_in[0];
  const int*   ei   = (const int*)d_in[1];
  const float* W1   = (const float*)d_in[2];
  const float* as1  = (const float*)d_in[3];
  const float* ad1  = (const float*)d_in[4];
  const float* b1   = (const float*)d_in[5];
  const float* W2   = (const float*)d_in[6];
  const float* as2  = (const float*)d_in[7];
  const float* ad2  = (const float*)d_in[8];
  const float* b2   = (const float*)d_in[9];
  const float* W3   = (const float*)d_in[10];
  const float* as3  = (const float*)d_in[11];
  const float* ad3  = (const float*)d_in[12];
  const float* b3   = (const float*)d_in[13];
  const float* Wout = (const float*)d_in[14];
  const float* bout = (const float*)d_in[15];
  float* out = (float*)d_out;

  const int n = in_sizes[0] / 3;
  const int E = in_sizes[1] / 2;
  const int Etot = E + n;
  const int* src = ei;
  const int* dst = ei + E;
  const int NP = ((n - 1) >> PSH) + 1;   // partitions (n=100000 -> 25, <= PMAX)

  // workspace layout — transient packed pstage (uint32 x Etot = 13.2 MB) aliases the
  // float region; dead before the first transform_kernel writes bufH.
  float* ws = (float*)d_ws;
  float* bufH = ws;                               // n*32
  float* bufX = bufH + (size_t)n * 32;            // n*32
  float* asrc = bufX + (size_t)n * 32;            // n*2
  float* adst = asrc + (size_t)n * 2;             // n*2
  int* rowptr  = (int*)(adst + (size_t)n * 2);    // n
  int* cursor  = rowptr + n;                      // n
  int* bsum    = cursor + n;                      // 512
  int* pbase   = bsum + 512;                      // PMAX+1
  int* pcursor = pbase + PMAX + 1;                // PMAX
  int* deg     = pcursor + PMAX;                  // n   (deg+pcount zeroed together)
  int* pcount  = deg + n;                         // PMAX
  int* csr_src = pcount + PMAX;                   // Etot
  unsigned* pstage = (unsigned*)ws;               // Etot (aliases bufH..)

  const int nbN = (n + TPB - 1) / TPB;
  const int nbE = (Etot + TPB - 1) / TPB;
  const int G8  = (nbE + 7) / 8;
  const int nbW = (n + 3) / 4;

  // ---- CSR build ----
  zero_kernel<<<(n + PMAX + TPB - 1) / TPB, TPB, 0, stream>>>(deg, n + PMAX);  // deg + pcount
  phist_kernel<<<512, TPB, 0, stream>>>(dst, E, n, pcount);
  pscan_kernel<<<1, 64, 0, stream>>>(pcount, pbase, pcursor, NP);
  stage_kernel<<<512, TPB, 0, stream>>>(src, dst, E, n, NP, pcursor, pstage);
  deg_hist_kernel<<<NP * 8, TPB, 0, stream>>>(pstage, pbase, NP, n, deg);
  scanA_kernel<<<nbN, TPB, 0, stream>>>(deg, n, bsum);
  scanB_kernel<<<1, 512, 0, stream>>>(bsum, nbN);
  scanC_kernel<<<nbN, TPB, 0, stream>>>(deg, bsum, n, rowptr, cursor);
  final_scatter_kernel<<<8 * G8, TPB, 0, stream>>>(pstage, Etot, G8, pbase, NP, cursor, csr_src);

  // ---- layer 1: in=3, out=32, H=2 ----
  transform_kernel<3, 32, 2><<<nbN, TPB, 0, stream>>>(x, W1, as1, ad1, bufH, asrc, adst, n);
  node_gat12<<<nbW, TPB, 0, stream>>>(rowptr, deg, csr_src, asrc, adst, bufH, b1, bufX, n);

  // ---- layer 2: in=32, out=32, H=2 ----
  transform_kernel<32, 32, 2><<<nbN, TPB, 0, stream>>>(bufX, W2, as2, ad2, bufH, asrc, adst, n);
  node_gat12<<<nbW, TPB, 0, stream>>>(rowptr, deg, csr_src, asrc, adst, bufH, b2, bufX, n);

  // ---- layer 3: in=32, out=16, H=1 ----
  transform_kernel<32, 16, 1><<<nbN, TPB, 0, stream>>>(bufX, W3, as3, ad3, bufH, asrc, adst, n);
  node_gat3<<<nbW, TPB, 0, stream>>>(rowptr, deg, csr_src, asrc, adst, bufH, b3, Wout, bout, out, n);
}

// Round 8
// 677.269 us; speedup vs baseline: 1.6167x; 1.6167x over previous
//
#include <hip/hip_runtime.h>
#include <math.h>

#define TPB 256
#define PMAX 32        // max partitions
#define PSH 12         // partition = dst >> 12 (4096 nodes/partition; n <= 131072)
#define PW  4096       // nodes per partition
#define CHUNK 8192     // edges per block in stage2

__device__ __forceinline__ float leaky02(float x) { return x > 0.f ? x : 0.2f * x; }
__device__ __forceinline__ float eluf(float x) { return x > 0.f ? x : (expf(x) - 1.f); }

// ====================== CSR build ======================

__global__ void zero_kernel(int* __restrict__ p, int n) {
  int i = blockIdx.x * blockDim.x + threadIdx.x;
  if (i < n) p[i] = 0;
}

// per-partition edge counts (LDS-aggregated)
__global__ void phist_kernel(const int* __restrict__ dst, int E, int n, int* __restrict__ pcount) {
  __shared__ int lh[PMAX];
  if (threadIdx.x < PMAX) lh[threadIdx.x] = 0;
  __syncthreads();
  int stride = gridDim.x * blockDim.x;
  for (int idx = blockIdx.x * blockDim.x + threadIdx.x; idx < E + n; idx += stride) {
    int dd = (idx < E) ? dst[idx] : (idx - E);
    atomicAdd(&lh[dd >> PSH], 1);
  }
  __syncthreads();
  if (threadIdx.x < PMAX) {
    int v = lh[threadIdx.x];
    if (v) atomicAdd(&pcount[threadIdx.x], v);
  }
}

// exclusive scan of NP partition counts -> pbase (immutable) + pcursor (mutable)
__global__ void pscan_kernel(const int* __restrict__ pcount, int* __restrict__ pbase,
                             int* __restrict__ pcursor, int NP) {
  if (threadIdx.x == 0) {
    int acc = 0;
    for (int q = 0; q < NP; q++) {
      pbase[q] = acc; pcursor[q] = acc; acc += pcount[q];
    }
    pbase[NP] = acc;
  }
}

// Chunked two-pass partition scatter: count -> one global alloc per partition -> scatter.
// Packs (src << PSH) | (dst & (PW-1)) into one uint32.
__global__ __launch_bounds__(256) void stage2_kernel(const int* __restrict__ src,
                                                     const int* __restrict__ dst,
                                                     int E, int n, int NP,
                                                     int* __restrict__ pcursor,
                                                     unsigned* __restrict__ pstage) {
  __shared__ int lcnt[PMAX];
  __shared__ int lbase[PMAX];
  int Etot = E + n;
  int c0 = blockIdx.x * CHUNK;
  if (c0 >= Etot) return;
  int c1 = min(c0 + CHUNK, Etot);
  for (int j = threadIdx.x; j < NP; j += TPB) lcnt[j] = 0;
  __syncthreads();
  // pass 1: count
  for (int idx = c0 + threadIdx.x; idx < c1; idx += TPB) {
    int dd = (idx < E) ? dst[idx] : (idx - E);
    atomicAdd(&lcnt[dd >> PSH], 1);
  }
  __syncthreads();
  // allocate contiguous sub-ranges (one global atomic per partition per block)
  for (int j = threadIdx.x; j < NP; j += TPB) {
    lbase[j] = atomicAdd(&pcursor[j], lcnt[j]);
    lcnt[j] = 0;
  }
  __syncthreads();
  // pass 2: scatter packed words
  for (int idx = c0 + threadIdx.x; idx < c1; idx += TPB) {
    int ss, dd;
    if (idx < E) { ss = src[idx]; dd = dst[idx]; }
    else         { ss = dd = idx - E; }
    int p = dd >> PSH;
    int pos = lbase[p] + atomicAdd(&lcnt[p], 1);
    pstage[pos] = ((unsigned)ss << PSH) | (unsigned)(dd & (PW - 1));
  }
}

// Fused per-partition CSR finalize: LDS histogram -> local exclusive scan (+pbase[p] = exact
// global rowptr, since partitions are dst-contiguous) -> LDS-cursor scatter into the
// partition's contiguous csr_src region (single block per region -> fully combined writes).
__global__ __launch_bounds__(1024) void build_csr_kernel(const unsigned* __restrict__ pstage,
                                                         const int* __restrict__ pbase,
                                                         int nvtx,
                                                         int* __restrict__ rowptr,
                                                         int* __restrict__ csr_src) {
  __shared__ int lhist[PW];
  __shared__ int lcur[PW];
  __shared__ int tsum[1024];
  int t = threadIdx.x;
  int p = blockIdx.x;
  int base = pbase[p];
  int end = pbase[p + 1];
  int nodebase = p << PSH;
  for (int j = t; j < PW; j += 1024) lhist[j] = 0;
  __syncthreads();
  // pass 1: degree histogram
  for (int i = base + t; i < end; i += 1024)
    atomicAdd(&lhist[pstage[i] & (PW - 1)], 1);
  __syncthreads();
  // exclusive scan of 4096 counts: 4 per thread + 1024-wide Hillis-Steele
  int j0 = 4 * t;
  int v0 = lhist[j0], v1 = lhist[j0 + 1], v2 = lhist[j0 + 2], v3 = lhist[j0 + 3];
  int s = v0 + v1 + v2 + v3;
  tsum[t] = s;
  __syncthreads();
  for (int off = 1; off < 1024; off <<= 1) {
    int a = (t >= off) ? tsum[t - off] : 0;
    __syncthreads();
    tsum[t] += a;
    __syncthreads();
  }
  int acc = base + tsum[t] - s;  // global exclusive prefix
  int vals[4] = {v0, v1, v2, v3};
#pragma unroll
  for (int k = 0; k < 4; k++) {
    int node = nodebase + j0 + k;
    lcur[j0 + k] = acc;
    if (node < nvtx) rowptr[node] = acc;
    acc += vals[k];
  }
  __syncthreads();
  // pass 2: scatter src into per-dst slots (LDS cursors only)
  for (int i = base + t; i < end; i += 1024) {
    unsigned v = pstage[i];
    int pos = atomicAdd(&lcur[v & (PW - 1)], 1);
    csr_src[pos] = (int)(v >> PSH);
  }
  if (p == (int)gridDim.x - 1 && t == 0) rowptr[nvtx] = end;
}

// ====================== node transform (h = x@W, attn logits) ======================

template<int IN, int OUT, int H>
__global__ void transform_kernel(const float* __restrict__ x, const float* __restrict__ W,
                                 const float* __restrict__ a_src, const float* __restrict__ a_dst,
                                 float* __restrict__ h, float* __restrict__ asrc,
                                 float* __restrict__ adst, int n) {
  __shared__ float sW[IN * OUT];
  __shared__ float sa[2 * OUT];
  for (int i = threadIdx.x; i < IN * OUT; i += blockDim.x) sW[i] = W[i];
  if (threadIdx.x < OUT) {
    sa[threadIdx.x] = a_src[threadIdx.x];
    sa[OUT + threadIdx.x] = a_dst[threadIdx.x];
  }
  __syncthreads();
  int i = blockIdx.x * blockDim.x + threadIdx.x;
  if (i >= n) return;
  float xv[IN];
#pragma unroll
  for (int k = 0; k < IN; k++) xv[k] = x[(size_t)i * IN + k];
  float hv[OUT];
#pragma unroll
  for (int j = 0; j < OUT; j++) {
    float acc = 0.f;
#pragma unroll
    for (int k = 0; k < IN; k++) acc += xv[k] * sW[k * OUT + j];
    hv[j] = acc;
    h[(size_t)i * OUT + j] = acc;
  }
#pragma unroll
  for (int hh = 0; hh < H; hh++) {
    float as = 0.f, ad = 0.f;
#pragma unroll
    for (int c = 0; c < 16; c++) {
      as += hv[hh * 16 + c] * sa[hh * 16 + c];
      ad += hv[hh * 16 + c] * sa[OUT + hh * 16 + c];
    }
    asrc[i * H + hh] = as;
    adst[i * H + hh] = ad;
  }
}

// ====================== per-node GAT aggregation (1 wave / dst node) ======================

__global__ __launch_bounds__(256) void node_gat12(
    const int* __restrict__ rowptr,
    const int* __restrict__ csr_src,
    const float* __restrict__ asrc,  // [n*2]
    const float* __restrict__ adst,  // [n*2]
    const float* __restrict__ hfeat, // [n*32]
    const float* __restrict__ bias,  // [32]
    float* __restrict__ outb,        // [n*32]
    int n) {
  __shared__ int   s_sidx[4][64];
  __shared__ float s_a0[4][64];
  __shared__ float s_a1[4][64];
  int wid = threadIdx.x >> 6;
  int lane = threadIdx.x & 63;
  int i = (blockIdx.x * blockDim.x + threadIdx.x) >> 6;
  if (i >= n) return;
  int start = rowptr[i];
  int d = rowptr[i + 1] - start;
  float ad0 = adst[i * 2 + 0];
  float ad1 = adst[i * 2 + 1];

  // ---- pass 1: online softmax (max + expsum in one sweep) ----
  float m0 = -3.4e38f, s0 = 0.f, m1 = -3.4e38f, s1 = 0.f;
  for (int k = lane; k < d; k += 64) {
    int sidx = csr_src[start + k];
    float2 av = ((const float2*)asrc)[sidx];
    float e0 = leaky02(av.x + ad0);
    float e1 = leaky02(av.y + ad1);
    float nm0 = fmaxf(m0, e0);
    s0 = s0 * expf(m0 - nm0) + expf(e0 - nm0);
    m0 = nm0;
    float nm1 = fmaxf(m1, e1);
    s1 = s1 * expf(m1 - nm1) + expf(e1 - nm1);
    m1 = nm1;
  }
#pragma unroll
  for (int off = 32; off >= 1; off >>= 1) {
    float mo0 = __shfl_xor(m0, off), so0 = __shfl_xor(s0, off);
    float nm0 = fmaxf(m0, mo0);
    s0 = s0 * expf(m0 - nm0) + so0 * expf(mo0 - nm0);
    m0 = nm0;
    float mo1 = __shfl_xor(m1, off), so1 = __shfl_xor(s1, off);
    float nm1 = fmaxf(m1, mo1);
    s1 = s1 * expf(m1 - nm1) + so1 * expf(mo1 - nm1);
    m1 = nm1;
  }
  float inv0 = 1.f / (s0 + 1e-16f);
  float inv1 = 1.f / (s1 + 1e-16f);

  // ---- pass 2: per-edge alpha staged in LDS; strided gather-accumulate ----
  int head = (lane >> 4) & 1;
  int c = lane & 31;
  int half = lane >> 5;
  float acc = 0.f;
  for (int base = 0; base < d; base += 64) {
    int k = base + lane;
    int sidx = 0;
    float a0 = 0.f, a1 = 0.f;
    if (k < d) {
      sidx = csr_src[start + k];
      float2 av = ((const float2*)asrc)[sidx];
      a0 = expf(leaky02(av.x + ad0) - m0) * inv0;
      a1 = expf(leaky02(av.y + ad1) - m1) * inv1;
    }
    s_sidx[wid][lane] = sidx;
    s_a0[wid][lane] = a0;
    s_a1[wid][lane] = a1;
    int cnt = min(64, d - base);
    for (int jj = half; jj < cnt; jj += 2) {
      int sb = s_sidx[wid][jj];
      float wb = head ? s_a1[wid][jj] : s_a0[wid][jj];
      acc += wb * hfeat[(size_t)sb * 32 + c];
    }
  }
  acc += __shfl_xor(acc, 32);
  if (lane < 32) {
    outb[(size_t)i * 32 + c] = eluf(acc + bias[c]);
  }
}

__global__ __launch_bounds__(256) void node_gat3(
    const int* __restrict__ rowptr,
    const int* __restrict__ csr_src,
    const float* __restrict__ asrc,  // [n]
    const float* __restrict__ adst,  // [n]
    const float* __restrict__ hfeat, // [n*16]
    const float* __restrict__ b3,    // [16]
    const float* __restrict__ Wout,  // [16]
    const float* __restrict__ bout,  // [1]
    float* __restrict__ out,         // [n] sigmoid ++ [n*16] embeddings
    int n) {
  __shared__ int   s_sidx[4][64];
  __shared__ float s_a0[4][64];
  int wid = threadIdx.x >> 6;
  int lane = threadIdx.x & 63;
  int i = (blockIdx.x * blockDim.x + threadIdx.x) >> 6;
  if (i >= n) return;
  int start = rowptr[i];
  int d = rowptr[i + 1] - start;
  float ad0 = adst[i];

  float m0 = -3.4e38f, s0 = 0.f;
  for (int k = lane; k < d; k += 64) {
    int sidx = csr_src[start + k];
    float e0 = leaky02(asrc[sidx] + ad0);
    float nm0 = fmaxf(m0, e0);
    s0 = s0 * expf(m0 - nm0) + expf(e0 - nm0);
    m0 = nm0;
  }
#pragma unroll
  for (int off = 32; off >= 1; off >>= 1) {
    float mo = __shfl_xor(m0, off), so = __shfl_xor(s0, off);
    float nm = fmaxf(m0, mo);
    s0 = s0 * expf(m0 - nm) + so * expf(mo - nm);
    m0 = nm;
  }
  float inv = 1.f / (s0 + 1e-16f);

  int c = lane & 15;
  int quarter = lane >> 4;
  float acc = 0.f;
  for (int base = 0; base < d; base += 64) {
    int k = base + lane;
    int sidx = 0;
    float a0 = 0.f;
    if (k < d) {
      sidx = csr_src[start + k];
      a0 = expf(leaky02(asrc[sidx] + ad0) - m0) * inv;
    }
    s_sidx[wid][lane] = sidx;
    s_a0[wid][lane] = a0;
    int cnt = min(64, d - base);
    for (int jj = quarter; jj < cnt; jj += 4) {
      int sb = s_sidx[wid][jj];
      acc += s_a0[wid][jj] * hfeat[(size_t)sb * 16 + c];
    }
  }
  acc += __shfl_xor(acc, 32);
  acc += __shfl_xor(acc, 16);

  float v = 0.f, z = 0.f;
  if (lane < 16) {
    v = eluf(acc + b3[c]);
    out[(size_t)n + (size_t)i * 16 + c] = v;
    z = v * Wout[c];
  }
#pragma unroll
  for (int off = 8; off >= 1; off >>= 1) z += __shfl_xor(z, off);
  if (lane == 0) out[i] = 1.f / (1.f + expf(-(z + bout[0])));
}

// ====================== launch ======================

extern "C" void kernel_launch(void* const* d_in, const int* in_sizes, int n_in,
                              void* d_out, int out_size, void* d_ws, size_t ws_size,
                              hipStream_t stream) {
  const float* x    = (const float*)d_in[0];
  const int*   ei   = (const int*)d_in[1];
  const float* W1   = (const float*)d_in[2];
  const float* as1  = (const float*)d_in[3];
  const float* ad1  = (const float*)d_in[4];
  const float* b1   = (const float*)d_in[5];
  const float* W2   = (const float*)d_in[6];
  const float* as2  = (const float*)d_in[7];
  const float* ad2  = (const float*)d_in[8];
  const float* b2   = (const float*)d_in[9];
  const float* W3   = (const float*)d_in[10];
  const float* as3  = (const float*)d_in[11];
  const float* ad3  = (const float*)d_in[12];
  const float* b3   = (const float*)d_in[13];
  const float* Wout = (const float*)d_in[14];
  const float* bout = (const float*)d_in[15];
  float* out = (float*)d_out;

  const int n = in_sizes[0] / 3;
  const int E = in_sizes[1] / 2;
  const int Etot = E + n;
  const int* src = ei;
  const int* dst = ei + E;
  const int NP = ((n - 1) >> PSH) + 1;   // n=100000 -> 25 partitions

  // workspace layout — transient packed pstage (uint32 x Etot = 13.2 MB) aliases the
  // float region; dead before the first transform_kernel writes bufH.
  float* ws = (float*)d_ws;
  float* bufH = ws;                               // n*32
  float* bufX = bufH + (size_t)n * 32;            // n*32
  float* asrc = bufX + (size_t)n * 32;            // n*2
  float* adst = asrc + (size_t)n * 2;             // n*2
  int* rowptr  = (int*)(adst + (size_t)n * 2);    // n+1
  int* pbase   = rowptr + n + 1;                  // PMAX+1
  int* pcursor = pbase + PMAX + 1;                // PMAX
  int* pcount  = pcursor + PMAX;                  // PMAX
  int* csr_src = pcount + PMAX;                   // Etot
  unsigned* pstage = (unsigned*)ws;               // Etot (aliases bufH..)

  const int nbN = (n + TPB - 1) / TPB;
  const int nbC = (Etot + CHUNK - 1) / CHUNK;
  const int nbW = (n + 3) / 4;

  // ---- CSR build ----
  zero_kernel<<<1, 64, 0, stream>>>(pcount, PMAX);
  phist_kernel<<<512, TPB, 0, stream>>>(dst, E, n, pcount);
  pscan_kernel<<<1, 64, 0, stream>>>(pcount, pbase, pcursor, NP);
  stage2_kernel<<<nbC, TPB, 0, stream>>>(src, dst, E, n, NP, pcursor, pstage);
  build_csr_kernel<<<NP, 1024, 0, stream>>>(pstage, pbase, n, rowptr, csr_src);

  // ---- layer 1: in=3, out=32, H=2 ----
  transform_kernel<3, 32, 2><<<nbN, TPB, 0, stream>>>(x, W1, as1, ad1, bufH, asrc, adst, n);
  node_gat12<<<nbW, TPB, 0, stream>>>(rowptr, csr_src, asrc, adst, bufH, b1, bufX, n);

  // ---- layer 2: in=32, out=32, H=2 ----
  transform_kernel<32, 32, 2><<<nbN, TPB, 0, stream>>>(bufX, W2, as2, ad2, bufH, asrc, adst, n);
  node_gat12<<<nbW, TPB, 0, stream>>>(rowptr, csr_src, asrc, adst, bufH, b2, bufX, n);

  // ---- layer 3: in=32, out=16, H=1 ----
  transform_kernel<32, 16, 1><<<nbN, TPB, 0, stream>>>(bufX, W3, as3, ad3, bufH, asrc, adst, n);
  node_gat3<<<nbW, TPB, 0, stream>>>(rowptr, csr_src, asrc, adst, bufH, b3, Wout, bout, out, n);
}

// Round 9
// 499.863 us; speedup vs baseline: 2.1905x; 1.3549x over previous
//
#include <hip/hip_runtime.h>
#include <math.h>

#define TPB 256
#define PMAX 32        // max partitions
#define PSH 12         // partition = dst >> 12 (4096 nodes/partition; n <= 131072)
#define PW  4096       // nodes per partition
#define CHUNK 8192     // edges per block in stage2

__device__ __forceinline__ float leaky02(float x) { return x > 0.f ? x : 0.2f * x; }
__device__ __forceinline__ float eluf(float x) { return x > 0.f ? x : (expf(x) - 1.f); }

// ====================== CSR build (R8-verified) ======================

__global__ void zero_kernel(int* __restrict__ p, int n) {
  int i = blockIdx.x * blockDim.x + threadIdx.x;
  if (i < n) p[i] = 0;
}

__global__ void phist_kernel(const int* __restrict__ dst, int E, int n, int* __restrict__ pcount) {
  __shared__ int lh[PMAX];
  if (threadIdx.x < PMAX) lh[threadIdx.x] = 0;
  __syncthreads();
  int stride = gridDim.x * blockDim.x;
  for (int idx = blockIdx.x * blockDim.x + threadIdx.x; idx < E + n; idx += stride) {
    int dd = (idx < E) ? dst[idx] : (idx - E);
    atomicAdd(&lh[dd >> PSH], 1);
  }
  __syncthreads();
  if (threadIdx.x < PMAX) {
    int v = lh[threadIdx.x];
    if (v) atomicAdd(&pcount[threadIdx.x], v);
  }
}

__global__ void pscan_kernel(const int* __restrict__ pcount, int* __restrict__ pbase,
                             int* __restrict__ pcursor, int NP) {
  if (threadIdx.x == 0) {
    int acc = 0;
    for (int q = 0; q < NP; q++) {
      pbase[q] = acc; pcursor[q] = acc; acc += pcount[q];
    }
    pbase[NP] = acc;
  }
}

__global__ __launch_bounds__(256) void stage2_kernel(const int* __restrict__ src,
                                                     const int* __restrict__ dst,
                                                     int E, int n, int NP,
                                                     int* __restrict__ pcursor,
                                                     unsigned* __restrict__ pstage) {
  __shared__ int lcnt[PMAX];
  __shared__ int lbase[PMAX];
  int Etot = E + n;
  int c0 = blockIdx.x * CHUNK;
  if (c0 >= Etot) return;
  int c1 = min(c0 + CHUNK, Etot);
  for (int j = threadIdx.x; j < NP; j += TPB) lcnt[j] = 0;
  __syncthreads();
  for (int idx = c0 + threadIdx.x; idx < c1; idx += TPB) {
    int dd = (idx < E) ? dst[idx] : (idx - E);
    atomicAdd(&lcnt[dd >> PSH], 1);
  }
  __syncthreads();
  for (int j = threadIdx.x; j < NP; j += TPB) {
    lbase[j] = atomicAdd(&pcursor[j], lcnt[j]);
    lcnt[j] = 0;
  }
  __syncthreads();
  for (int idx = c0 + threadIdx.x; idx < c1; idx += TPB) {
    int ss, dd;
    if (idx < E) { ss = src[idx]; dd = dst[idx]; }
    else         { ss = dd = idx - E; }
    int p = dd >> PSH;
    int pos = lbase[p] + atomicAdd(&lcnt[p], 1);
    pstage[pos] = ((unsigned)ss << PSH) | (unsigned)(dd & (PW - 1));
  }
}

__global__ __launch_bounds__(1024) void build_csr_kernel(const unsigned* __restrict__ pstage,
                                                         const int* __restrict__ pbase,
                                                         int nvtx,
                                                         int* __restrict__ rowptr,
                                                         int* __restrict__ csr_src) {
  __shared__ int lhist[PW];
  __shared__ int lcur[PW];
  __shared__ int tsum[1024];
  int t = threadIdx.x;
  int p = blockIdx.x;
  int base = pbase[p];
  int end = pbase[p + 1];
  int nodebase = p << PSH;
  for (int j = t; j < PW; j += 1024) lhist[j] = 0;
  __syncthreads();
  for (int i = base + t; i < end; i += 1024)
    atomicAdd(&lhist[pstage[i] & (PW - 1)], 1);
  __syncthreads();
  int j0 = 4 * t;
  int v0 = lhist[j0], v1 = lhist[j0 + 1], v2 = lhist[j0 + 2], v3 = lhist[j0 + 3];
  int s = v0 + v1 + v2 + v3;
  tsum[t] = s;
  __syncthreads();
  for (int off = 1; off < 1024; off <<= 1) {
    int a = (t >= off) ? tsum[t - off] : 0;
    __syncthreads();
    tsum[t] += a;
    __syncthreads();
  }
  int acc = base + tsum[t] - s;
  int vals[4] = {v0, v1, v2, v3};
#pragma unroll
  for (int k = 0; k < 4; k++) {
    int node = nodebase + j0 + k;
    lcur[j0 + k] = acc;
    if (node < nvtx) rowptr[node] = acc;
    acc += vals[k];
  }
  __syncthreads();
  for (int i = base + t; i < end; i += 1024) {
    unsigned v = pstage[i];
    int pos = atomicAdd(&lcur[v & (PW - 1)], 1);
    csr_src[pos] = (int)(v >> PSH);
  }
  if (p == (int)gridDim.x - 1 && t == 0) rowptr[nvtx] = end;
}

// ====================== node transform (h = x@W, attn logits) ======================

template<int IN, int OUT, int H>
__global__ void transform_kernel(const float* __restrict__ x, const float* __restrict__ W,
                                 const float* __restrict__ a_src, const float* __restrict__ a_dst,
                                 float* __restrict__ h, float* __restrict__ asrc,
                                 float* __restrict__ adst, int n) {
  __shared__ float sW[IN * OUT];
  __shared__ float sa[2 * OUT];
  for (int i = threadIdx.x; i < IN * OUT; i += blockDim.x) sW[i] = W[i];
  if (threadIdx.x < OUT) {
    sa[threadIdx.x] = a_src[threadIdx.x];
    sa[OUT + threadIdx.x] = a_dst[threadIdx.x];
  }
  __syncthreads();
  int i = blockIdx.x * blockDim.x + threadIdx.x;
  if (i >= n) return;
  float xv[IN];
#pragma unroll
  for (int k = 0; k < IN; k++) xv[k] = x[(size_t)i * IN + k];
  float hv[OUT];
#pragma unroll
  for (int j = 0; j < OUT; j++) {
    float acc = 0.f;
#pragma unroll
    for (int k = 0; k < IN; k++) acc += xv[k] * sW[k * OUT + j];
    hv[j] = acc;
    h[(size_t)i * OUT + j] = acc;
  }
#pragma unroll
  for (int hh = 0; hh < H; hh++) {
    float as = 0.f, ad = 0.f;
#pragma unroll
    for (int c = 0; c < 16; c++) {
      as += hv[hh * 16 + c] * sa[hh * 16 + c];
      ad += hv[hh * 16 + c] * sa[OUT + hh * 16 + c];
    }
    asrc[i * H + hh] = as;
    adst[i * H + hh] = ad;
  }
}

// ====================== per-node GAT aggregation (1 wave / dst node) ======================
// Classic 2-pass softmax (max sweep -> single expf/edge/head), unnormalized accumulate,
// float4 gather: 8-lane group per edge, each lane owns 4 channels.

__global__ __launch_bounds__(256) void node_gat12(
    const int* __restrict__ rowptr,
    const int* __restrict__ csr_src,
    const float* __restrict__ asrc,  // [n*2]
    const float* __restrict__ adst,  // [n*2]
    const float* __restrict__ hfeat, // [n*32]
    const float* __restrict__ bias,  // [32]
    float* __restrict__ outb,        // [n*32]
    int n) {
  __shared__ int   s_sidx[4][64];
  __shared__ float s_w0[4][64];
  __shared__ float s_w1[4][64];
  int wid = threadIdx.x >> 6;
  int lane = threadIdx.x & 63;
  int i = (blockIdx.x * blockDim.x + threadIdx.x) >> 6;
  if (i >= n) return;
  int start = rowptr[i];
  int d = rowptr[i + 1] - start;
  float ad0 = adst[i * 2 + 0];
  float ad1 = adst[i * 2 + 1];
  const float4* hf4 = (const float4*)hfeat;
  int g = lane >> 3;   // edge group 0..7
  int q = lane & 7;    // float4 channel slot (q<4: head0, q>=4: head1)
  float4 acc = make_float4(0.f, 0.f, 0.f, 0.f);
  float sl0 = 0.f, sl1 = 0.f;

  if (d <= 64) {
    // ---- fast path: single edge block, load once ----
    int sidx = 0;
    float e0 = -3.4e38f, e1 = -3.4e38f;
    if (lane < d) {
      sidx = csr_src[start + lane];
      float2 av = ((const float2*)asrc)[sidx];
      e0 = leaky02(av.x + ad0);
      e1 = leaky02(av.y + ad1);
    }
    float m0 = e0, m1 = e1;
#pragma unroll
    for (int off = 32; off >= 1; off >>= 1) {
      m0 = fmaxf(m0, __shfl_xor(m0, off));
      m1 = fmaxf(m1, __shfl_xor(m1, off));
    }
    float w0 = 0.f, w1 = 0.f;
    if (lane < d) { w0 = expf(e0 - m0); w1 = expf(e1 - m1); }
    sl0 = w0; sl1 = w1;
    s_sidx[wid][lane] = sidx;
    s_w0[wid][lane] = w0;
    s_w1[wid][lane] = w1;
    // same-wave LDS write->read ordering (R4-verified)
    for (int jj = g; jj < d; jj += 8) {
      int sb = s_sidx[wid][jj];
      float w = (q >= 4) ? s_w1[wid][jj] : s_w0[wid][jj];
      float4 hv = hf4[(size_t)sb * 8 + q];
      acc.x += w * hv.x; acc.y += w * hv.y; acc.z += w * hv.z; acc.w += w * hv.w;
    }
  } else {
    // ---- general path ----
    float m0 = -3.4e38f, m1 = -3.4e38f;
    for (int k = lane; k < d; k += 64) {
      int sidx = csr_src[start + k];
      float2 av = ((const float2*)asrc)[sidx];
      m0 = fmaxf(m0, leaky02(av.x + ad0));
      m1 = fmaxf(m1, leaky02(av.y + ad1));
    }
#pragma unroll
    for (int off = 32; off >= 1; off >>= 1) {
      m0 = fmaxf(m0, __shfl_xor(m0, off));
      m1 = fmaxf(m1, __shfl_xor(m1, off));
    }
    for (int base = 0; base < d; base += 64) {
      int k = base + lane;
      int sidx = 0;
      float w0 = 0.f, w1 = 0.f;
      if (k < d) {
        sidx = csr_src[start + k];
        float2 av = ((const float2*)asrc)[sidx];
        w0 = expf(leaky02(av.x + ad0) - m0);
        w1 = expf(leaky02(av.y + ad1) - m1);
        sl0 += w0; sl1 += w1;
      }
      s_sidx[wid][lane] = sidx;
      s_w0[wid][lane] = w0;
      s_w1[wid][lane] = w1;
      int cnt = min(64, d - base);
      for (int jj = g; jj < cnt; jj += 8) {
        int sb = s_sidx[wid][jj];
        float w = (q >= 4) ? s_w1[wid][jj] : s_w0[wid][jj];
        float4 hv = hf4[(size_t)sb * 8 + q];
        acc.x += w * hv.x; acc.y += w * hv.y; acc.z += w * hv.z; acc.w += w * hv.w;
      }
    }
  }

  // reduce exp-sums across wave
#pragma unroll
  for (int off = 32; off >= 1; off >>= 1) {
    sl0 += __shfl_xor(sl0, off);
    sl1 += __shfl_xor(sl1, off);
  }
  // reduce acc over the 8 edge-groups (lanes with same q)
#pragma unroll
  for (int off = 8; off <= 32; off <<= 1) {
    acc.x += __shfl_xor(acc.x, off);
    acc.y += __shfl_xor(acc.y, off);
    acc.z += __shfl_xor(acc.z, off);
    acc.w += __shfl_xor(acc.w, off);
  }
  if (lane < 8) {
    float inv = 1.f / (((lane >= 4) ? sl1 : sl0) + 1e-16f);
    float4 bv = ((const float4*)bias)[lane];
    float4 o;
    o.x = eluf(acc.x * inv + bv.x);
    o.y = eluf(acc.y * inv + bv.y);
    o.z = eluf(acc.z * inv + bv.z);
    o.w = eluf(acc.w * inv + bv.w);
    ((float4*)outb)[(size_t)i * 8 + lane] = o;
  }
}

__global__ __launch_bounds__(256) void node_gat3(
    const int* __restrict__ rowptr,
    const int* __restrict__ csr_src,
    const float* __restrict__ asrc,  // [n]
    const float* __restrict__ adst,  // [n]
    const float* __restrict__ hfeat, // [n*16]
    const float* __restrict__ b3,    // [16]
    const float* __restrict__ Wout,  // [16]
    const float* __restrict__ bout,  // [1]
    float* __restrict__ out,         // [n] sigmoid ++ [n*16] embeddings
    int n) {
  __shared__ int   s_sidx[4][64];
  __shared__ float s_w0[4][64];
  int wid = threadIdx.x >> 6;
  int lane = threadIdx.x & 63;
  int i = (blockIdx.x * blockDim.x + threadIdx.x) >> 6;
  if (i >= n) return;
  int start = rowptr[i];
  int d = rowptr[i + 1] - start;
  float ad0 = adst[i];
  const float4* hf4 = (const float4*)hfeat;
  int g = lane >> 2;   // edge group 0..15
  int q = lane & 3;    // float4 channel slot
  float4 acc = make_float4(0.f, 0.f, 0.f, 0.f);
  float sl = 0.f;

  if (d <= 64) {
    int sidx = 0;
    float e0 = -3.4e38f;
    if (lane < d) {
      sidx = csr_src[start + lane];
      e0 = leaky02(asrc[sidx] + ad0);
    }
    float m0 = e0;
#pragma unroll
    for (int off = 32; off >= 1; off >>= 1) m0 = fmaxf(m0, __shfl_xor(m0, off));
    float w0 = (lane < d) ? expf(e0 - m0) : 0.f;
    sl = w0;
    s_sidx[wid][lane] = sidx;
    s_w0[wid][lane] = w0;
    for (int jj = g; jj < d; jj += 16) {
      int sb = s_sidx[wid][jj];
      float w = s_w0[wid][jj];
      float4 hv = hf4[(size_t)sb * 4 + q];
      acc.x += w * hv.x; acc.y += w * hv.y; acc.z += w * hv.z; acc.w += w * hv.w;
    }
  } else {
    float m0 = -3.4e38f;
    for (int k = lane; k < d; k += 64) {
      int sidx = csr_src[start + k];
      m0 = fmaxf(m0, leaky02(asrc[sidx] + ad0));
    }
#pragma unroll
    for (int off = 32; off >= 1; off >>= 1) m0 = fmaxf(m0, __shfl_xor(m0, off));
    for (int base = 0; base < d; base += 64) {
      int k = base + lane;
      int sidx = 0;
      float w0 = 0.f;
      if (k < d) {
        sidx = csr_src[start + k];
        w0 = expf(leaky02(asrc[sidx] + ad0) - m0);
        sl += w0;
      }
      s_sidx[wid][lane] = sidx;
      s_w0[wid][lane] = w0;
      int cnt = min(64, d - base);
      for (int jj = g; jj < cnt; jj += 16) {
        int sb = s_sidx[wid][jj];
        float w = s_w0[wid][jj];
        float4 hv = hf4[(size_t)sb * 4 + q];
        acc.x += w * hv.x; acc.y += w * hv.y; acc.z += w * hv.z; acc.w += w * hv.w;
      }
    }
  }

#pragma unroll
  for (int off = 32; off >= 1; off >>= 1) sl += __shfl_xor(sl, off);
#pragma unroll
  for (int off = 4; off <= 32; off <<= 1) {
    acc.x += __shfl_xor(acc.x, off);
    acc.y += __shfl_xor(acc.y, off);
    acc.z += __shfl_xor(acc.z, off);
    acc.w += __shfl_xor(acc.w, off);
  }
  float z = 0.f;
  if (lane < 4) {
    float inv = 1.f / (sl + 1e-16f);
    float4 bv = ((const float4*)b3)[lane];
    float4 wv = ((const float4*)Wout)[lane];
    float4 o;
    o.x = eluf(acc.x * inv + bv.x);
    o.y = eluf(acc.y * inv + bv.y);
    o.z = eluf(acc.z * inv + bv.z);
    o.w = eluf(acc.w * inv + bv.w);
    ((float4*)(out + n))[(size_t)i * 4 + lane] = o;
    z = o.x * wv.x + o.y * wv.y + o.z * wv.z + o.w * wv.w;
  }
  z += __shfl_xor(z, 1);
  z += __shfl_xor(z, 2);
  if (lane == 0) out[i] = 1.f / (1.f + expf(-(z + bout[0])));
}

// ====================== launch ======================

extern "C" void kernel_launch(void* const* d_in, const int* in_sizes, int n_in,
                              void* d_out, int out_size, void* d_ws, size_t ws_size,
                              hipStream_t stream) {
  const float* x    = (const float*)d_in[0];
  const int*   ei   = (const int*)d_in[1];
  const float* W1   = (const float*)d_in[2];
  const float* as1  = (const float*)d_in[3];
  const float* ad1  = (const float*)d_in[4];
  const float* b1   = (const float*)d_in[5];
  const float* W2   = (const float*)d_in[6];
  const float* as2  = (const float*)d_in[7];
  const float* ad2  = (const float*)d_in[8];
  const float* b2   = (const float*)d_in[9];
  const float* W3   = (const float*)d_in[10];
  const float* as3  = (const float*)d_in[11];
  const float* ad3  = (const float*)d_in[12];
  const float* b3   = (const float*)d_in[13];
  const float* Wout = (const float*)d_in[14];
  const float* bout = (const float*)d_in[15];
  float* out = (float*)d_out;

  const int n = in_sizes[0] / 3;
  const int E = in_sizes[1] / 2;
  const int Etot = E + n;
  const int* src = ei;
  const int* dst = ei + E;
  const int NP = ((n - 1) >> PSH) + 1;   // n=100000 -> 25 partitions

  float* ws = (float*)d_ws;
  float* bufH = ws;                               // n*32
  float* bufX = bufH + (size_t)n * 32;            // n*32
  float* asrc = bufX + (size_t)n * 32;            // n*2
  float* adst = asrc + (size_t)n * 2;             // n*2
  int* rowptr  = (int*)(adst + (size_t)n * 2);    // n+1
  int* pbase   = rowptr + n + 1;                  // PMAX+1
  int* pcursor = pbase + PMAX + 1;                // PMAX
  int* pcount  = pcursor + PMAX;                  // PMAX
  int* csr_src = pcount + PMAX;                   // Etot
  unsigned* pstage = (unsigned*)ws;               // Etot (aliases bufH..; dead before transforms)

  const int nbN = (n + TPB - 1) / TPB;
  const int nbC = (Etot + CHUNK - 1) / CHUNK;
  const int nbW = (n + 3) / 4;

  // ---- CSR build ----
  zero_kernel<<<1, 64, 0, stream>>>(pcount, PMAX);
  phist_kernel<<<512, TPB, 0, stream>>>(dst, E, n, pcount);
  pscan_kernel<<<1, 64, 0, stream>>>(pcount, pbase, pcursor, NP);
  stage2_kernel<<<nbC, TPB, 0, stream>>>(src, dst, E, n, NP, pcursor, pstage);
  build_csr_kernel<<<NP, 1024, 0, stream>>>(pstage, pbase, n, rowptr, csr_src);

  // ---- layer 1: in=3, out=32, H=2 ----
  transform_kernel<3, 32, 2><<<nbN, TPB, 0, stream>>>(x, W1, as1, ad1, bufH, asrc, adst, n);
  node_gat12<<<nbW, TPB, 0, stream>>>(rowptr, csr_src, asrc, adst, bufH, b1, bufX, n);

  // ---- layer 2: in=32, out=32, H=2 ----
  transform_kernel<32, 32, 2><<<nbN, TPB, 0, stream>>>(bufX, W2, as2, ad2, bufH, asrc, adst, n);
  node_gat12<<<nbW, TPB, 0, stream>>>(rowptr, csr_src, asrc, adst, bufH, b2, bufX, n);

  // ---- layer 3: in=32, out=16, H=1 ----
  transform_kernel<32, 16, 1><<<nbN, TPB, 0, stream>>>(bufX, W3, as3, ad3, bufH, asrc, adst, n);
  node_gat3<<<nbW, TPB, 0, stream>>>(rowptr, csr_src, asrc, adst, bufH, b3, Wout, bout, out, n);
}

// Round 10
// 436.885 us; speedup vs baseline: 2.5063x; 1.1442x over previous
//
#include <hip/hip_runtime.h>
#include <math.h>

#define TPB 256
#define PMAX 128       // max partitions
#define PSH 10         // partition = dst >> 10 (1024 nodes/partition; n <= 131072)
#define PW  1024       // nodes per partition
#define CHUNK 8192     // edges per block in stage2

__device__ __forceinline__ float leaky02(float x) { return x > 0.f ? x : 0.2f * x; }
__device__ __forceinline__ float eluf(float x) { return x > 0.f ? x : (expf(x) - 1.f); }

// ====================== CSR build ======================

__global__ void zero_kernel(int* __restrict__ p, int n) {
  int i = blockIdx.x * blockDim.x + threadIdx.x;
  if (i < n) p[i] = 0;
}

__global__ void phist_kernel(const int* __restrict__ dst, int E, int n, int* __restrict__ pcount) {
  __shared__ int lh[PMAX];
  if (threadIdx.x < PMAX) lh[threadIdx.x] = 0;
  __syncthreads();
  int stride = gridDim.x * blockDim.x;
  for (int idx = blockIdx.x * blockDim.x + threadIdx.x; idx < E + n; idx += stride) {
    int dd = (idx < E) ? dst[idx] : (idx - E);
    atomicAdd(&lh[dd >> PSH], 1);
  }
  __syncthreads();
  if (threadIdx.x < PMAX) {
    int v = lh[threadIdx.x];
    if (v) atomicAdd(&pcount[threadIdx.x], v);
  }
}

__global__ void pscan_kernel(const int* __restrict__ pcount, int* __restrict__ pbase,
                             int* __restrict__ pcursor, int NP) {
  if (threadIdx.x == 0) {
    int acc = 0;
    for (int q = 0; q < NP; q++) {
      pbase[q] = acc; pcursor[q] = acc; acc += pcount[q];
    }
    pbase[NP] = acc;
  }
}

__global__ __launch_bounds__(256) void stage2_kernel(const int* __restrict__ src,
                                                     const int* __restrict__ dst,
                                                     int E, int n, int NP,
                                                     int* __restrict__ pcursor,
                                                     unsigned* __restrict__ pstage) {
  __shared__ int lcnt[PMAX];
  __shared__ int lbase[PMAX];
  int Etot = E + n;
  int c0 = blockIdx.x * CHUNK;
  if (c0 >= Etot) return;
  int c1 = min(c0 + CHUNK, Etot);
  for (int j = threadIdx.x; j < NP; j += TPB) lcnt[j] = 0;
  __syncthreads();
  for (int idx = c0 + threadIdx.x; idx < c1; idx += TPB) {
    int dd = (idx < E) ? dst[idx] : (idx - E);
    atomicAdd(&lcnt[dd >> PSH], 1);
  }
  __syncthreads();
  for (int j = threadIdx.x; j < NP; j += TPB) {
    lbase[j] = atomicAdd(&pcursor[j], lcnt[j]);
    lcnt[j] = 0;
  }
  __syncthreads();
  for (int idx = c0 + threadIdx.x; idx < c1; idx += TPB) {
    int ss, dd;
    if (idx < E) { ss = src[idx]; dd = dst[idx]; }
    else         { ss = dd = idx - E; }
    int p = dd >> PSH;
    int pos = lbase[p] + atomicAdd(&lcnt[p], 1);
    pstage[pos] = ((unsigned)ss << PSH) | (unsigned)(dd & (PW - 1));
  }
}

// One 1024-thread block per partition; PW=1024 -> one hist entry per thread.
__global__ __launch_bounds__(1024) void build_csr_kernel(const unsigned* __restrict__ pstage,
                                                         const int* __restrict__ pbase,
                                                         int nvtx,
                                                         int* __restrict__ rowptr,
                                                         int* __restrict__ csr_src) {
  __shared__ int lhist[PW];
  __shared__ int lcur[PW];
  int t = threadIdx.x;
  int p = blockIdx.x;
  int base = pbase[p];
  int end = pbase[p + 1];
  int nodebase = p << PSH;
  lhist[t] = 0;
  __syncthreads();
  // degree histogram
  for (int i = base + t; i < end; i += 1024)
    atomicAdd(&lhist[pstage[i] & (PW - 1)], 1);
  __syncthreads();
  // exclusive scan over 1024 entries (Hillis-Steele in lcur as scratch)
  int v = lhist[t];
  lcur[t] = v;
  __syncthreads();
  for (int off = 1; off < 1024; off <<= 1) {
    int a = (t >= off) ? lcur[t - off] : 0;
    __syncthreads();
    lcur[t] += a;
    __syncthreads();
  }
  int acc = base + lcur[t] - v;  // global exclusive prefix
  __syncthreads();
  lcur[t] = acc;
  int node = nodebase + t;
  if (node < nvtx) rowptr[node] = acc;
  __syncthreads();
  // scatter src into per-dst slots (LDS cursors only; block owns contiguous csr region)
  for (int i = base + t; i < end; i += 1024) {
    unsigned w = pstage[i];
    int pos = atomicAdd(&lcur[w & (PW - 1)], 1);
    csr_src[pos] = (int)(w >> PSH);
  }
  if (p == (int)gridDim.x - 1 && t == 0) rowptr[nvtx] = end;
}

// ====================== node transform (h = x@W, attn logits) ======================

template<int IN, int OUT, int H>
__global__ void transform_kernel(const float* __restrict__ x, const float* __restrict__ W,
                                 const float* __restrict__ a_src, const float* __restrict__ a_dst,
                                 float* __restrict__ h, float* __restrict__ asrc,
                                 float* __restrict__ adst, int n) {
  __shared__ float sW[IN * OUT];
  __shared__ float sa[2 * OUT];
  for (int i = threadIdx.x; i < IN * OUT; i += blockDim.x) sW[i] = W[i];
  if (threadIdx.x < OUT) {
    sa[threadIdx.x] = a_src[threadIdx.x];
    sa[OUT + threadIdx.x] = a_dst[threadIdx.x];
  }
  __syncthreads();
  int i = blockIdx.x * blockDim.x + threadIdx.x;
  if (i >= n) return;
  float xv[IN];
#pragma unroll
  for (int k = 0; k < IN; k++) xv[k] = x[(size_t)i * IN + k];
  float hv[OUT];
#pragma unroll
  for (int j = 0; j < OUT; j++) {
    float acc = 0.f;
#pragma unroll
    for (int k = 0; k < IN; k++) acc += xv[k] * sW[k * OUT + j];
    hv[j] = acc;
    h[(size_t)i * OUT + j] = acc;
  }
#pragma unroll
  for (int hh = 0; hh < H; hh++) {
    float as = 0.f, ad = 0.f;
#pragma unroll
    for (int c = 0; c < 16; c++) {
      as += hv[hh * 16 + c] * sa[hh * 16 + c];
      ad += hv[hh * 16 + c] * sa[OUT + hh * 16 + c];
    }
    asrc[i * H + hh] = as;
    adst[i * H + hh] = ad;
  }
}

// ====================== per-node GAT aggregation (1 wave / dst node, R9-verified) ======================

__global__ __launch_bounds__(256) void node_gat12(
    const int* __restrict__ rowptr,
    const int* __restrict__ csr_src,
    const float* __restrict__ asrc,  // [n*2]
    const float* __restrict__ adst,  // [n*2]
    const float* __restrict__ hfeat, // [n*32]
    const float* __restrict__ bias,  // [32]
    float* __restrict__ outb,        // [n*32]
    int n) {
  __shared__ int   s_sidx[4][64];
  __shared__ float s_w0[4][64];
  __shared__ float s_w1[4][64];
  int wid = threadIdx.x >> 6;
  int lane = threadIdx.x & 63;
  int i = (blockIdx.x * blockDim.x + threadIdx.x) >> 6;
  if (i >= n) return;
  int start = rowptr[i];
  int d = rowptr[i + 1] - start;
  float ad0 = adst[i * 2 + 0];
  float ad1 = adst[i * 2 + 1];
  const float4* hf4 = (const float4*)hfeat;
  int g = lane >> 3;   // edge group 0..7
  int q = lane & 7;    // float4 channel slot (q<4: head0, q>=4: head1)
  float4 acc = make_float4(0.f, 0.f, 0.f, 0.f);
  float sl0 = 0.f, sl1 = 0.f;

  if (d <= 64) {
    int sidx = 0;
    float e0 = -3.4e38f, e1 = -3.4e38f;
    if (lane < d) {
      sidx = csr_src[start + lane];
      float2 av = ((const float2*)asrc)[sidx];
      e0 = leaky02(av.x + ad0);
      e1 = leaky02(av.y + ad1);
    }
    float m0 = e0, m1 = e1;
#pragma unroll
    for (int off = 32; off >= 1; off >>= 1) {
      m0 = fmaxf(m0, __shfl_xor(m0, off));
      m1 = fmaxf(m1, __shfl_xor(m1, off));
    }
    float w0 = 0.f, w1 = 0.f;
    if (lane < d) { w0 = expf(e0 - m0); w1 = expf(e1 - m1); }
    sl0 = w0; sl1 = w1;
    s_sidx[wid][lane] = sidx;
    s_w0[wid][lane] = w0;
    s_w1[wid][lane] = w1;
    for (int jj = g; jj < d; jj += 8) {
      int sb = s_sidx[wid][jj];
      float w = (q >= 4) ? s_w1[wid][jj] : s_w0[wid][jj];
      float4 hv = hf4[(size_t)sb * 8 + q];
      acc.x += w * hv.x; acc.y += w * hv.y; acc.z += w * hv.z; acc.w += w * hv.w;
    }
  } else {
    float m0 = -3.4e38f, m1 = -3.4e38f;
    for (int k = lane; k < d; k += 64) {
      int sidx = csr_src[start + k];
      float2 av = ((const float2*)asrc)[sidx];
      m0 = fmaxf(m0, leaky02(av.x + ad0));
      m1 = fmaxf(m1, leaky02(av.y + ad1));
    }
#pragma unroll
    for (int off = 32; off >= 1; off >>= 1) {
      m0 = fmaxf(m0, __shfl_xor(m0, off));
      m1 = fmaxf(m1, __shfl_xor(m1, off));
    }
    for (int base = 0; base < d; base += 64) {
      int k = base + lane;
      int sidx = 0;
      float w0 = 0.f, w1 = 0.f;
      if (k < d) {
        sidx = csr_src[start + k];
        float2 av = ((const float2*)asrc)[sidx];
        w0 = expf(leaky02(av.x + ad0) - m0);
        w1 = expf(leaky02(av.y + ad1) - m1);
        sl0 += w0; sl1 += w1;
      }
      s_sidx[wid][lane] = sidx;
      s_w0[wid][lane] = w0;
      s_w1[wid][lane] = w1;
      int cnt = min(64, d - base);
      for (int jj = g; jj < cnt; jj += 8) {
        int sb = s_sidx[wid][jj];
        float w = (q >= 4) ? s_w1[wid][jj] : s_w0[wid][jj];
        float4 hv = hf4[(size_t)sb * 8 + q];
        acc.x += w * hv.x; acc.y += w * hv.y; acc.z += w * hv.z; acc.w += w * hv.w;
      }
    }
  }

#pragma unroll
  for (int off = 32; off >= 1; off >>= 1) {
    sl0 += __shfl_xor(sl0, off);
    sl1 += __shfl_xor(sl1, off);
  }
#pragma unroll
  for (int off = 8; off <= 32; off <<= 1) {
    acc.x += __shfl_xor(acc.x, off);
    acc.y += __shfl_xor(acc.y, off);
    acc.z += __shfl_xor(acc.z, off);
    acc.w += __shfl_xor(acc.w, off);
  }
  if (lane < 8) {
    float inv = 1.f / (((lane >= 4) ? sl1 : sl0) + 1e-16f);
    float4 bv = ((const float4*)bias)[lane];
    float4 o;
    o.x = eluf(acc.x * inv + bv.x);
    o.y = eluf(acc.y * inv + bv.y);
    o.z = eluf(acc.z * inv + bv.z);
    o.w = eluf(acc.w * inv + bv.w);
    ((float4*)outb)[(size_t)i * 8 + lane] = o;
  }
}

__global__ __launch_bounds__(256) void node_gat3(
    const int* __restrict__ rowptr,
    const int* __restrict__ csr_src,
    const float* __restrict__ asrc,  // [n]
    const float* __restrict__ adst,  // [n]
    const float* __restrict__ hfeat, // [n*16]
    const float* __restrict__ b3,    // [16]
    const float* __restrict__ Wout,  // [16]
    const float* __restrict__ bout,  // [1]
    float* __restrict__ out,         // [n] sigmoid ++ [n*16] embeddings
    int n) {
  __shared__ int   s_sidx[4][64];
  __shared__ float s_w0[4][64];
  int wid = threadIdx.x >> 6;
  int lane = threadIdx.x & 63;
  int i = (blockIdx.x * blockDim.x + threadIdx.x) >> 6;
  if (i >= n) return;
  int start = rowptr[i];
  int d = rowptr[i + 1] - start;
  float ad0 = adst[i];
  const float4* hf4 = (const float4*)hfeat;
  int g = lane >> 2;   // edge group 0..15
  int q = lane & 3;    // float4 channel slot
  float4 acc = make_float4(0.f, 0.f, 0.f, 0.f);
  float sl = 0.f;

  if (d <= 64) {
    int sidx = 0;
    float e0 = -3.4e38f;
    if (lane < d) {
      sidx = csr_src[start + lane];
      e0 = leaky02(asrc[sidx] + ad0);
    }
    float m0 = e0;
#pragma unroll
    for (int off = 32; off >= 1; off >>= 1) m0 = fmaxf(m0, __shfl_xor(m0, off));
    float w0 = (lane < d) ? expf(e0 - m0) : 0.f;
    sl = w0;
    s_sidx[wid][lane] = sidx;
    s_w0[wid][lane] = w0;
    for (int jj = g; jj < d; jj += 16) {
      int sb = s_sidx[wid][jj];
      float w = s_w0[wid][jj];
      float4 hv = hf4[(size_t)sb * 4 + q];
      acc.x += w * hv.x; acc.y += w * hv.y; acc.z += w * hv.z; acc.w += w * hv.w;
    }
  } else {
    float m0 = -3.4e38f;
    for (int k = lane; k < d; k += 64) {
      int sidx = csr_src[start + k];
      m0 = fmaxf(m0, leaky02(asrc[sidx] + ad0));
    }
#pragma unroll
    for (int off = 32; off >= 1; off >>= 1) m0 = fmaxf(m0, __shfl_xor(m0, off));
    for (int base = 0; base < d; base += 64) {
      int k = base + lane;
      int sidx = 0;
      float w0 = 0.f;
      if (k < d) {
        sidx = csr_src[start + k];
        w0 = expf(leaky02(asrc[sidx] + ad0) - m0);
        sl += w0;
      }
      s_sidx[wid][lane] = sidx;
      s_w0[wid][lane] = w0;
      int cnt = min(64, d - base);
      for (int jj = g; jj < cnt; jj += 16) {
        int sb = s_sidx[wid][jj];
        float w = s_w0[wid][jj];
        float4 hv = hf4[(size_t)sb * 4 + q];
        acc.x += w * hv.x; acc.y += w * hv.y; acc.z += w * hv.z; acc.w += w * hv.w;
      }
    }
  }

#pragma unroll
  for (int off = 32; off >= 1; off >>= 1) sl += __shfl_xor(sl, off);
#pragma unroll
  for (int off = 4; off <= 32; off <<= 1) {
    acc.x += __shfl_xor(acc.x, off);
    acc.y += __shfl_xor(acc.y, off);
    acc.z += __shfl_xor(acc.z, off);
    acc.w += __shfl_xor(acc.w, off);
  }
  float z = 0.f;
  if (lane < 4) {
    float inv = 1.f / (sl + 1e-16f);
    float4 bv = ((const float4*)b3)[lane];
    float4 wv = ((const float4*)Wout)[lane];
    float4 o;
    o.x = eluf(acc.x * inv + bv.x);
    o.y = eluf(acc.y * inv + bv.y);
    o.z = eluf(acc.z * inv + bv.z);
    o.w = eluf(acc.w * inv + bv.w);
    ((float4*)(out + n))[(size_t)i * 4 + lane] = o;
    z = o.x * wv.x + o.y * wv.y + o.z * wv.z + o.w * wv.w;
  }
  z += __shfl_xor(z, 1);
  z += __shfl_xor(z, 2);
  if (lane == 0) out[i] = 1.f / (1.f + expf(-(z + bout[0])));
}

// ====================== launch ======================

extern "C" void kernel_launch(void* const* d_in, const int* in_sizes, int n_in,
                              void* d_out, int out_size, void* d_ws, size_t ws_size,
                              hipStream_t stream) {
  const float* x    = (const float*)d_in[0];
  const int*   ei   = (const int*)d_in[1];
  const float* W1   = (const float*)d_in[2];
  const float* as1  = (const float*)d_in[3];
  const float* ad1  = (const float*)d_in[4];
  const float* b1   = (const float*)d_in[5];
  const float* W2   = (const float*)d_in[6];
  const float* as2  = (const float*)d_in[7];
  const float* ad2  = (const float*)d_in[8];
  const float* b2   = (const float*)d_in[9];
  const float* W3   = (const float*)d_in[10];
  const float* as3  = (const float*)d_in[11];
  const float* ad3  = (const float*)d_in[12];
  const float* b3   = (const float*)d_in[13];
  const float* Wout = (const float*)d_in[14];
  const float* bout = (const float*)d_in[15];
  float* out = (float*)d_out;

  const int n = in_sizes[0] / 3;
  const int E = in_sizes[1] / 2;
  const int Etot = E + n;
  const int* src = ei;
  const int* dst = ei + E;
  const int NP = ((n - 1) >> PSH) + 1;   // n=100000 -> 98 partitions

  float* ws = (float*)d_ws;
  float* bufH = ws;                               // n*32
  float* bufX = bufH + (size_t)n * 32;            // n*32
  float* asrc = bufX + (size_t)n * 32;            // n*2
  float* adst = asrc + (size_t)n * 2;             // n*2
  int* rowptr  = (int*)(adst + (size_t)n * 2);    // n+1
  int* pbase   = rowptr + n + 1;                  // PMAX+1
  int* pcursor = pbase + PMAX + 1;                // PMAX
  int* pcount  = pcursor + PMAX;                  // PMAX
  int* csr_src = pcount + PMAX;                   // Etot
  unsigned* pstage = (unsigned*)ws;               // Etot (aliases bufH..; dead before transforms)

  const int nbN = (n + TPB - 1) / TPB;
  const int nbC = (Etot + CHUNK - 1) / CHUNK;
  const int nbW = (n + 3) / 4;

  // ---- CSR build ----
  zero_kernel<<<1, PMAX, 0, stream>>>(pcount, PMAX);
  phist_kernel<<<512, TPB, 0, stream>>>(dst, E, n, pcount);
  pscan_kernel<<<1, 64, 0, stream>>>(pcount, pbase, pcursor, NP);
  stage2_kernel<<<nbC, TPB, 0, stream>>>(src, dst, E, n, NP, pcursor, pstage);
  build_csr_kernel<<<NP, 1024, 0, stream>>>(pstage, pbase, n, rowptr, csr_src);

  // ---- layer 1: in=3, out=32, H=2 ----
  transform_kernel<3, 32, 2><<<nbN, TPB, 0, stream>>>(x, W1, as1, ad1, bufH, asrc, adst, n);
  node_gat12<<<nbW, TPB, 0, stream>>>(rowptr, csr_src, asrc, adst, bufH, b1, bufX, n);

  // ---- layer 2: in=32, out=32, H=2 ----
  transform_kernel<32, 32, 2><<<nbN, TPB, 0, stream>>>(bufX, W2, as2, ad2, bufH, asrc, adst, n);
  node_gat12<<<nbW, TPB, 0, stream>>>(rowptr, csr_src, asrc, adst, bufH, b2, bufX, n);

  // ---- layer 3: in=32, out=16, H=1 ----
  transform_kernel<32, 16, 1><<<nbN, TPB, 0, stream>>>(bufX, W3, as3, ad3, bufH, asrc, adst, n);
  node_gat3<<<nbW, TPB, 0, stream>>>(rowptr, csr_src, asrc, adst, bufH, b3, Wout, bout, out, n);
}

// Round 11
// 427.440 us; speedup vs baseline: 2.5617x; 1.0221x over previous
//
#include <hip/hip_runtime.h>
#include <math.h>

#define TPB 256
#define PMAX 128       // max partitions
#define PSH 10         // partition = dst >> 10 (1024 nodes/partition; n <= 131072)
#define PW  1024       // nodes per partition
#define CHUNK 8192     // edges per block in count/scatter

__device__ __forceinline__ float leaky02(float x) { return x > 0.f ? x : 0.2f * x; }
__device__ __forceinline__ float eluf(float x) { return x > 0.f ? x : (expf(x) - 1.f); }

// ====================== CSR build (radix-style: count -> scan -> scatter -> finalize) ======================

__global__ void zero_kernel(int* __restrict__ p, int n) {
  int i = blockIdx.x * blockDim.x + threadIdx.x;
  if (i < n) p[i] = 0;
}

// chunked per-block partition count; persists counts[b][p] for the scatter pass.
__global__ __launch_bounds__(256) void count_kernel(const int* __restrict__ dst, int E, int n,
                                                    int* __restrict__ counts,
                                                    int* __restrict__ pcount) {
  __shared__ int lcnt[PMAX];
  int Etot = E + n;
  int c0 = blockIdx.x * CHUNK;
  if (c0 >= Etot) return;
  int c1 = min(c0 + CHUNK, Etot);
  for (int j = threadIdx.x; j < PMAX; j += TPB) lcnt[j] = 0;
  __syncthreads();
  for (int idx = c0 + threadIdx.x; idx < c1; idx += TPB) {
    int dd = (idx < E) ? dst[idx] : (idx - E);
    atomicAdd(&lcnt[dd >> PSH], 1);
  }
  __syncthreads();
  for (int j = threadIdx.x; j < PMAX; j += TPB) {
    int v = lcnt[j];
    counts[blockIdx.x * PMAX + j] = v;
    if (v) atomicAdd(&pcount[j], v);
  }
}

__global__ void pscan_kernel(const int* __restrict__ pcount, int* __restrict__ pbase,
                             int* __restrict__ pcursor, int NP) {
  if (threadIdx.x == 0) {
    int acc = 0;
    for (int q = 0; q < NP; q++) {
      pbase[q] = acc; pcursor[q] = acc; acc += pcount[q];
    }
    pbase[NP] = acc;
  }
}

// scatter using the persisted counts (no recount): 128 global atomics per block.
__global__ __launch_bounds__(256) void scatter_kernel(const int* __restrict__ src,
                                                      const int* __restrict__ dst,
                                                      int E, int n,
                                                      const int* __restrict__ counts,
                                                      int* __restrict__ pcursor,
                                                      unsigned* __restrict__ pstage) {
  __shared__ int lbase[PMAX];
  __shared__ int lcnt[PMAX];
  int Etot = E + n;
  int c0 = blockIdx.x * CHUNK;
  if (c0 >= Etot) return;
  int c1 = min(c0 + CHUNK, Etot);
  for (int j = threadIdx.x; j < PMAX; j += TPB) {
    int c = counts[blockIdx.x * PMAX + j];
    lbase[j] = atomicAdd(&pcursor[j], c);
    lcnt[j] = 0;
  }
  __syncthreads();
  for (int idx = c0 + threadIdx.x; idx < c1; idx += TPB) {
    int ss, dd;
    if (idx < E) { ss = src[idx]; dd = dst[idx]; }
    else         { ss = dd = idx - E; }
    int p = dd >> PSH;
    int pos = lbase[p] + atomicAdd(&lcnt[p], 1);
    pstage[pos] = ((unsigned)ss << PSH) | (unsigned)(dd & (PW - 1));
  }
}

// One 1024-thread block per partition; PW=1024 -> one hist entry per thread.
__global__ __launch_bounds__(1024) void build_csr_kernel(const unsigned* __restrict__ pstage,
                                                         const int* __restrict__ pbase,
                                                         int nvtx,
                                                         int* __restrict__ rowptr,
                                                         int* __restrict__ csr_src) {
  __shared__ int lhist[PW];
  __shared__ int lcur[PW];
  int t = threadIdx.x;
  int p = blockIdx.x;
  int base = pbase[p];
  int end = pbase[p + 1];
  int nodebase = p << PSH;
  lhist[t] = 0;
  __syncthreads();
  for (int i = base + t; i < end; i += 1024)
    atomicAdd(&lhist[pstage[i] & (PW - 1)], 1);
  __syncthreads();
  int v = lhist[t];
  lcur[t] = v;
  __syncthreads();
  for (int off = 1; off < 1024; off <<= 1) {
    int a = (t >= off) ? lcur[t - off] : 0;
    __syncthreads();
    lcur[t] += a;
    __syncthreads();
  }
  int acc = base + lcur[t] - v;
  __syncthreads();
  lcur[t] = acc;
  int node = nodebase + t;
  if (node < nvtx) rowptr[node] = acc;
  __syncthreads();
  for (int i = base + t; i < end; i += 1024) {
    unsigned w = pstage[i];
    int pos = atomicAdd(&lcur[w & (PW - 1)], 1);
    csr_src[pos] = (int)(w >> PSH);
  }
  if (p == (int)gridDim.x - 1 && t == 0) rowptr[nvtx] = end;
}

// ====================== node transform (h = x@W, attn logits) ======================

template<int IN, int OUT, int H>
__global__ void transform_kernel(const float* __restrict__ x, const float* __restrict__ W,
                                 const float* __restrict__ a_src, const float* __restrict__ a_dst,
                                 float* __restrict__ h, float* __restrict__ asrc,
                                 float* __restrict__ adst, int n) {
  __shared__ float sW[IN * OUT];
  __shared__ float sa[2 * OUT];
  for (int i = threadIdx.x; i < IN * OUT; i += blockDim.x) sW[i] = W[i];
  if (threadIdx.x < OUT) {
    sa[threadIdx.x] = a_src[threadIdx.x];
    sa[OUT + threadIdx.x] = a_dst[threadIdx.x];
  }
  __syncthreads();
  int i = blockIdx.x * blockDim.x + threadIdx.x;
  if (i >= n) return;
  float xv[IN];
#pragma unroll
  for (int k = 0; k < IN; k++) xv[k] = x[(size_t)i * IN + k];
  float hv[OUT];
#pragma unroll
  for (int j = 0; j < OUT; j++) {
    float acc = 0.f;
#pragma unroll
    for (int k = 0; k < IN; k++) acc += xv[k] * sW[k * OUT + j];
    hv[j] = acc;
    h[(size_t)i * OUT + j] = acc;
  }
#pragma unroll
  for (int hh = 0; hh < H; hh++) {
    float as = 0.f, ad = 0.f;
#pragma unroll
    for (int c = 0; c < 16; c++) {
      as += hv[hh * 16 + c] * sa[hh * 16 + c];
      ad += hv[hh * 16 + c] * sa[OUT + hh * 16 + c];
    }
    asrc[i * H + hh] = as;
    adst[i * H + hh] = ad;
  }
}

// ====================== per-node GAT aggregation (1 wave / dst node) ======================
// Packed (sidx,w) float2 LDS: one ds_read_b64 in the hot gather loop.

__global__ __launch_bounds__(256) void node_gat12(
    const int* __restrict__ rowptr,
    const int* __restrict__ csr_src,
    const float* __restrict__ asrc,  // [n*2]
    const float* __restrict__ adst,  // [n*2]
    const float* __restrict__ hfeat, // [n*32]
    const float* __restrict__ bias,  // [32]
    float* __restrict__ outb,        // [n*32]
    int n) {
  __shared__ float2 s_h0[4][64];   // (bitcast sidx, w0)
  __shared__ float2 s_h1[4][64];   // (bitcast sidx, w1)
  int wid = threadIdx.x >> 6;
  int lane = threadIdx.x & 63;
  int i = (blockIdx.x * blockDim.x + threadIdx.x) >> 6;
  if (i >= n) return;
  int start = rowptr[i];
  int d = rowptr[i + 1] - start;
  float ad0 = adst[i * 2 + 0];
  float ad1 = adst[i * 2 + 1];
  const float4* hf4 = (const float4*)hfeat;
  int g = lane >> 3;   // edge group 0..7
  int q = lane & 7;    // float4 channel slot (q<4: head0, q>=4: head1)
  float4 acc = make_float4(0.f, 0.f, 0.f, 0.f);
  float sl0 = 0.f, sl1 = 0.f;

  if (d <= 64) {
    int sidx = 0;
    float e0 = -3.4e38f, e1 = -3.4e38f;
    if (lane < d) {
      sidx = csr_src[start + lane];
      float2 av = ((const float2*)asrc)[sidx];
      e0 = leaky02(av.x + ad0);
      e1 = leaky02(av.y + ad1);
    }
    float m0 = e0, m1 = e1;
#pragma unroll
    for (int off = 32; off >= 1; off >>= 1) {
      m0 = fmaxf(m0, __shfl_xor(m0, off));
      m1 = fmaxf(m1, __shfl_xor(m1, off));
    }
    float w0 = 0.f, w1 = 0.f;
    if (lane < d) { w0 = expf(e0 - m0); w1 = expf(e1 - m1); }
    sl0 = w0; sl1 = w1;
    s_h0[wid][lane] = make_float2(__int_as_float(sidx), w0);
    s_h1[wid][lane] = make_float2(__int_as_float(sidx), w1);
    // same-wave LDS write->read ordering (R4-verified)
    for (int jj = g; jj < d; jj += 8) {
      float2 pw = (q >= 4) ? s_h1[wid][jj] : s_h0[wid][jj];
      int sb = __float_as_int(pw.x);
      float w = pw.y;
      float4 hv = hf4[(size_t)sb * 8 + q];
      acc.x += w * hv.x; acc.y += w * hv.y; acc.z += w * hv.z; acc.w += w * hv.w;
    }
  } else {
    float m0 = -3.4e38f, m1 = -3.4e38f;
    for (int k = lane; k < d; k += 64) {
      int sidx = csr_src[start + k];
      float2 av = ((const float2*)asrc)[sidx];
      m0 = fmaxf(m0, leaky02(av.x + ad0));
      m1 = fmaxf(m1, leaky02(av.y + ad1));
    }
#pragma unroll
    for (int off = 32; off >= 1; off >>= 1) {
      m0 = fmaxf(m0, __shfl_xor(m0, off));
      m1 = fmaxf(m1, __shfl_xor(m1, off));
    }
    for (int base = 0; base < d; base += 64) {
      int k = base + lane;
      int sidx = 0;
      float w0 = 0.f, w1 = 0.f;
      if (k < d) {
        sidx = csr_src[start + k];
        float2 av = ((const float2*)asrc)[sidx];
        w0 = expf(leaky02(av.x + ad0) - m0);
        w1 = expf(leaky02(av.y + ad1) - m1);
        sl0 += w0; sl1 += w1;
      }
      s_h0[wid][lane] = make_float2(__int_as_float(sidx), w0);
      s_h1[wid][lane] = make_float2(__int_as_float(sidx), w1);
      int cnt = min(64, d - base);
      for (int jj = g; jj < cnt; jj += 8) {
        float2 pw = (q >= 4) ? s_h1[wid][jj] : s_h0[wid][jj];
        int sb = __float_as_int(pw.x);
        float w = pw.y;
        float4 hv = hf4[(size_t)sb * 8 + q];
        acc.x += w * hv.x; acc.y += w * hv.y; acc.z += w * hv.z; acc.w += w * hv.w;
      }
    }
  }

#pragma unroll
  for (int off = 32; off >= 1; off >>= 1) {
    sl0 += __shfl_xor(sl0, off);
    sl1 += __shfl_xor(sl1, off);
  }
#pragma unroll
  for (int off = 8; off <= 32; off <<= 1) {
    acc.x += __shfl_xor(acc.x, off);
    acc.y += __shfl_xor(acc.y, off);
    acc.z += __shfl_xor(acc.z, off);
    acc.w += __shfl_xor(acc.w, off);
  }
  if (lane < 8) {
    float inv = 1.f / (((lane >= 4) ? sl1 : sl0) + 1e-16f);
    float4 bv = ((const float4*)bias)[lane];
    float4 o;
    o.x = eluf(acc.x * inv + bv.x);
    o.y = eluf(acc.y * inv + bv.y);
    o.z = eluf(acc.z * inv + bv.z);
    o.w = eluf(acc.w * inv + bv.w);
    ((float4*)outb)[(size_t)i * 8 + lane] = o;
  }
}

__global__ __launch_bounds__(256) void node_gat3(
    const int* __restrict__ rowptr,
    const int* __restrict__ csr_src,
    const float* __restrict__ asrc,  // [n]
    const float* __restrict__ adst,  // [n]
    const float* __restrict__ hfeat, // [n*16]
    const float* __restrict__ b3,    // [16]
    const float* __restrict__ Wout,  // [16]
    const float* __restrict__ bout,  // [1]
    float* __restrict__ out,         // [n] sigmoid ++ [n*16] embeddings
    int n) {
  __shared__ float2 s_hw[4][64];   // (bitcast sidx, w)
  int wid = threadIdx.x >> 6;
  int lane = threadIdx.x & 63;
  int i = (blockIdx.x * blockDim.x + threadIdx.x) >> 6;
  if (i >= n) return;
  int start = rowptr[i];
  int d = rowptr[i + 1] - start;
  float ad0 = adst[i];
  const float4* hf4 = (const float4*)hfeat;
  int g = lane >> 2;   // edge group 0..15
  int q = lane & 3;    // float4 channel slot
  float4 acc = make_float4(0.f, 0.f, 0.f, 0.f);
  float sl = 0.f;

  if (d <= 64) {
    int sidx = 0;
    float e0 = -3.4e38f;
    if (lane < d) {
      sidx = csr_src[start + lane];
      e0 = leaky02(asrc[sidx] + ad0);
    }
    float m0 = e0;
#pragma unroll
    for (int off = 32; off >= 1; off >>= 1) m0 = fmaxf(m0, __shfl_xor(m0, off));
    float w0 = (lane < d) ? expf(e0 - m0) : 0.f;
    sl = w0;
    s_hw[wid][lane] = make_float2(__int_as_float(sidx), w0);
    for (int jj = g; jj < d; jj += 16) {
      float2 pw = s_hw[wid][jj];
      int sb = __float_as_int(pw.x);
      float w = pw.y;
      float4 hv = hf4[(size_t)sb * 4 + q];
      acc.x += w * hv.x; acc.y += w * hv.y; acc.z += w * hv.z; acc.w += w * hv.w;
    }
  } else {
    float m0 = -3.4e38f;
    for (int k = lane; k < d; k += 64) {
      int sidx = csr_src[start + k];
      m0 = fmaxf(m0, leaky02(asrc[sidx] + ad0));
    }
#pragma unroll
    for (int off = 32; off >= 1; off >>= 1) m0 = fmaxf(m0, __shfl_xor(m0, off));
    for (int base = 0; base < d; base += 64) {
      int k = base + lane;
      int sidx = 0;
      float w0 = 0.f;
      if (k < d) {
        sidx = csr_src[start + k];
        w0 = expf(leaky02(asrc[sidx] + ad0) - m0);
        sl += w0;
      }
      s_hw[wid][lane] = make_float2(__int_as_float(sidx), w0);
      int cnt = min(64, d - base);
      for (int jj = g; jj < cnt; jj += 16) {
        float2 pw = s_hw[wid][jj];
        int sb = __float_as_int(pw.x);
        float w = pw.y;
        float4 hv = hf4[(size_t)sb * 4 + q];
        acc.x += w * hv.x; acc.y += w * hv.y; acc.z += w * hv.z; acc.w += w * hv.w;
      }
    }
  }

#pragma unroll
  for (int off = 32; off >= 1; off >>= 1) sl += __shfl_xor(sl, off);
#pragma unroll
  for (int off = 4; off <= 32; off <<= 1) {
    acc.x += __shfl_xor(acc.x, off);
    acc.y += __shfl_xor(acc.y, off);
    acc.z += __shfl_xor(acc.z, off);
    acc.w += __shfl_xor(acc.w, off);
  }
  float z = 0.f;
  if (lane < 4) {
    float inv = 1.f / (sl + 1e-16f);
    float4 bv = ((const float4*)b3)[lane];
    float4 wv = ((const float4*)Wout)[lane];
    float4 o;
    o.x = eluf(acc.x * inv + bv.x);
    o.y = eluf(acc.y * inv + bv.y);
    o.z = eluf(acc.z * inv + bv.z);
    o.w = eluf(acc.w * inv + bv.w);
    ((float4*)(out + n))[(size_t)i * 4 + lane] = o;
    z = o.x * wv.x + o.y * wv.y + o.z * wv.z + o.w * wv.w;
  }
  z += __shfl_xor(z, 1);
  z += __shfl_xor(z, 2);
  if (lane == 0) out[i] = 1.f / (1.f + expf(-(z + bout[0])));
}

// ====================== launch ======================

extern "C" void kernel_launch(void* const* d_in, const int* in_sizes, int n_in,
                              void* d_out, int out_size, void* d_ws, size_t ws_size,
                              hipStream_t stream) {
  const float* x    = (const float*)d_in[0];
  const int*   ei   = (const int*)d_in[1];
  const float* W1   = (const float*)d_in[2];
  const float* as1  = (const float*)d_in[3];
  const float* ad1  = (const float*)d_in[4];
  const float* b1   = (const float*)d_in[5];
  const float* W2   = (const float*)d_in[6];
  const float* as2  = (const float*)d_in[7];
  const float* ad2  = (const float*)d_in[8];
  const float* b2   = (const float*)d_in[9];
  const float* W3   = (const float*)d_in[10];
  const float* as3  = (const float*)d_in[11];
  const float* ad3  = (const float*)d_in[12];
  const float* b3   = (const float*)d_in[13];
  const float* Wout = (const float*)d_in[14];
  const float* bout = (const float*)d_in[15];
  float* out = (float*)d_out;

  const int n = in_sizes[0] / 3;
  const int E = in_sizes[1] / 2;
  const int Etot = E + n;
  const int* src = ei;
  const int* dst = ei + E;
  const int NP = ((n - 1) >> PSH) + 1;   // n=100000 -> 98 partitions
  const int nbC = (Etot + CHUNK - 1) / CHUNK;

  float* ws = (float*)d_ws;
  float* bufH = ws;                               // n*32
  float* bufX = bufH + (size_t)n * 32;            // n*32
  float* asrc = bufX + (size_t)n * 32;            // n*2
  float* adst = asrc + (size_t)n * 2;             // n*2
  int* rowptr  = (int*)(adst + (size_t)n * 2);    // n+1
  int* pbase   = rowptr + n + 1;                  // PMAX+1
  int* pcursor = pbase + PMAX + 1;                // PMAX
  int* pcount  = pcursor + PMAX;                  // PMAX
  int* csr_src = pcount + PMAX;                   // Etot
  int* counts  = csr_src + Etot;                  // nbC*PMAX (~207 KB)
  unsigned* pstage = (unsigned*)ws;               // Etot (aliases bufH..; dead before transforms)

  const int nbN = (n + TPB - 1) / TPB;
  const int nbW = (n + 3) / 4;

  // ---- CSR build ----
  zero_kernel<<<1, PMAX, 0, stream>>>(pcount, PMAX);
  count_kernel<<<nbC, TPB, 0, stream>>>(dst, E, n, counts, pcount);
  pscan_kernel<<<1, 64, 0, stream>>>(pcount, pbase, pcursor, NP);
  scatter_kernel<<<nbC, TPB, 0, stream>>>(src, dst, E, n, counts, pcursor, pstage);
  build_csr_kernel<<<NP, 1024, 0, stream>>>(pstage, pbase, n, rowptr, csr_src);

  // ---- layer 1: in=3, out=32, H=2 ----
  transform_kernel<3, 32, 2><<<nbN, TPB, 0, stream>>>(x, W1, as1, ad1, bufH, asrc, adst, n);
  node_gat12<<<nbW, TPB, 0, stream>>>(rowptr, csr_src, asrc, adst, bufH, b1, bufX, n);

  // ---- layer 2: in=32, out=32, H=2 ----
  transform_kernel<32, 32, 2><<<nbN, TPB, 0, stream>>>(bufX, W2, as2, ad2, bufH, asrc, adst, n);
  node_gat12<<<nbW, TPB, 0, stream>>>(rowptr, csr_src, asrc, adst, bufH, b2, bufX, n);

  // ---- layer 3: in=32, out=16, H=1 ----
  transform_kernel<32, 16, 1><<<nbN, TPB, 0, stream>>>(bufX, W3, as3, ad3, bufH, asrc, adst, n);
  node_gat3<<<nbW, TPB, 0, stream>>>(rowptr, csr_src, asrc, adst, bufH, b3, Wout, bout, out, n);
}